// Round 2
// baseline (1641.844 us; speedup 1.0000x reference)
//
#include <hip/hip_runtime.h>
#include <hip/hip_bf16.h>
#include <math.h>

#define BB 2
#define NN 512
#define CS 384
#define CZ 128
#define HH 12
#define DD 16
#define PP 4
#define PVV 8
#define CATW 2112

// W_L = sqrt(1/3); W_C*0.5 = 0.5*sqrt(2/36)
#define W_L_CONST 0.57735026919f
#define W_C_HALF 0.11785113019f
#define INV_SQRT_D 0.25f

// ---------------- Kernel 1: projections + rigid apply ----------------
// block per token (b*N+i), 256 threads
__global__ void k_proj(const float* __restrict__ s_i,
                       const float* __restrict__ rots,
                       const float* __restrict__ trans,
                       const float* __restrict__ wq,
                       const float* __restrict__ wk,
                       const float* __restrict__ wv,
                       const float* __restrict__ wqp,
                       const float* __restrict__ wkp,
                       const float* __restrict__ wvp,
                       float* __restrict__ qw, float* __restrict__ kw,
                       float* __restrict__ vw, float* __restrict__ tqw,
                       float* __restrict__ tkw, float* __restrict__ tvw) {
  int bi = blockIdx.x;
  __shared__ float s_row[CS];
  __shared__ float praw[576];  // qp(144) kp(144) vp(288) raw
  __shared__ float R[9], T[3];
  int tid = threadIdx.x;
  for (int idx = tid; idx < CS; idx += 256) s_row[idx] = s_i[(size_t)bi * CS + idx];
  if (tid < 9) R[tid] = rots[bi * 9 + tid];
  if (tid < 3) T[tid] = trans[bi * 3 + tid];
  __syncthreads();

  // q,k,v: 3*192 outputs
  for (int f = tid; f < 576; f += 256) {
    int sel = f / 192, r = f % 192;
    const float* w = (sel == 0) ? wq : (sel == 1) ? wk : wv;
    float acc = 0.f;
    #pragma unroll 4
    for (int c = 0; c < CS; c++) acc += s_row[c] * w[c * 192 + r];
    float* dst = (sel == 0) ? qw : (sel == 1) ? kw : vw;
    dst[(size_t)bi * 192 + r] = acc;
  }
  // point raws: qp 144, kp 144, vp 288
  for (int f = tid; f < 576; f += 256) {
    float acc = 0.f;
    if (f < 144) {
      #pragma unroll 4
      for (int c = 0; c < CS; c++) acc += s_row[c] * wqp[c * 144 + f];
    } else if (f < 288) {
      int r = f - 144;
      #pragma unroll 4
      for (int c = 0; c < CS; c++) acc += s_row[c] * wkp[c * 144 + r];
    } else {
      int r = f - 288;
      #pragma unroll 4
      for (int c = 0; c < CS; c++) acc += s_row[c] * wvp[c * 288 + r];
    }
    praw[f] = acc;
  }
  __syncthreads();
  // rigid apply: x_out[x] = sum_y R[x][y]*v[y] + t[x]
  for (int f = tid; f < 576; f += 256) {
    int base, r;
    float* dst;
    if (f < 144)      { r = f;       base = 0;   dst = tqw + (size_t)bi * 144; }
    else if (f < 288) { r = f - 144; base = 144; dst = tkw + (size_t)bi * 144; }
    else              { r = f - 288; base = 288; dst = tvw + (size_t)bi * 288; }
    int hp = r / 3, x = r % 3;
    float v0 = praw[base + hp * 3 + 0];
    float v1 = praw[base + hp * 3 + 1];
    float v2 = praw[base + hp * 3 + 2];
    dst[r] = R[x * 3 + 0] * v0 + R[x * 3 + 1] * v1 + R[x * 3 + 2] * v2 + T[x];
  }
}

// ---------------- Kernel 2: logits + softmax ----------------
// block per (b,i), 256 threads
__global__ void k_logits(const float* __restrict__ z,
                         const float* __restrict__ wb,
                         const float* __restrict__ gamma,
                         const float* __restrict__ qw,
                         const float* __restrict__ kw,
                         const float* __restrict__ tqw,
                         const float* __restrict__ tkw,
                         float* __restrict__ aw) {
  int bi = blockIdx.x;
  int b = bi / NN;
  __shared__ float qrow[192], tqrow[144], gam[HH];
  __shared__ float wbs[CZ * HH];        // [c][h]
  __shared__ float zt[32][129];         // 32-j tile, padded
  __shared__ float lg[HH][NN];          // logits
  __shared__ float red[256];
  int tid = threadIdx.x;
  for (int idx = tid; idx < 192; idx += 256) qrow[idx] = qw[(size_t)bi * 192 + idx];
  if (tid < 144) tqrow[tid] = tqw[(size_t)bi * 144 + tid];
  if (tid < HH) gam[tid] = gamma[tid];
  for (int idx = tid; idx < CZ * HH; idx += 256) wbs[idx] = wb[idx];
  __syncthreads();

  const float* zrow = z + (size_t)bi * NN * CZ;
  for (int jt = 0; jt < NN / 32; jt++) {
    __syncthreads();
    for (int idx = tid; idx < 32 * CZ; idx += 256) {
      int jl = idx / CZ, c = idx % CZ;
      zt[jl][c] = zrow[(size_t)(jt * 32 + jl) * CZ + c];
    }
    __syncthreads();
    for (int task = tid; task < 32 * HH; task += 256) {
      int jl = task / HH, h = task % HH;
      int j = jt * 32 + jl;
      float bij = 0.f;
      #pragma unroll 8
      for (int c = 0; c < CZ; c++) bij += zt[jl][c] * wbs[c * HH + h];
      const float* krow = kw + ((size_t)(b * NN + j)) * 192 + h * 16;
      float as = 0.f;
      #pragma unroll
      for (int d = 0; d < 16; d++) as += qrow[h * 16 + d] * krow[d];
      const float* tkrow = tkw + ((size_t)(b * NN + j)) * 144 + h * 12;
      float d2 = 0.f;
      #pragma unroll
      for (int e = 0; e < 12; e++) {
        float df = tqrow[h * 12 + e] - tkrow[e];
        d2 += df * df;
      }
      lg[h][j] = W_L_CONST * (as * INV_SQRT_D + bij - W_C_HALF * gam[h] * d2);
    }
  }
  __syncthreads();

  // softmax over j for each h
  for (int h = 0; h < HH; h++) {
    float m = fmaxf(lg[h][tid], lg[h][tid + 256]);
    red[tid] = m;
    __syncthreads();
    for (int s = 128; s > 0; s >>= 1) {
      if (tid < s) red[tid] = fmaxf(red[tid], red[tid + s]);
      __syncthreads();
    }
    float mx = red[0];
    __syncthreads();
    float e0 = __expf(lg[h][tid] - mx);
    float e1 = __expf(lg[h][tid + 256] - mx);
    red[tid] = e0 + e1;
    __syncthreads();
    for (int s = 128; s > 0; s >>= 1) {
      if (tid < s) red[tid] += red[tid + s];
      __syncthreads();
    }
    float inv = 1.0f / red[0];
    __syncthreads();
    float* arow = aw + ((size_t)bi * HH + h) * NN;
    arow[tid] = e0 * inv;
    arow[tid + 256] = e1 * inv;
  }
}

// ---------------- Kernel 3: outputs + cat assembly ----------------
// block per (b,i), 256 threads
__global__ void k_out(const float* __restrict__ z,
                      const float* __restrict__ vw,
                      const float* __restrict__ tvw,
                      const float* __restrict__ aw,
                      const float* __restrict__ rots,
                      const float* __restrict__ trans,
                      float* __restrict__ catm) {
  int bi = blockIdx.x;
  int b = bi / NN;
  __shared__ float al[HH][NN];   // attention row, 24 KB
  __shared__ float zt[32][129];
  __shared__ float praw[288];
  __shared__ float ohp[288];
  __shared__ float R[9], T[3];
  int tid = threadIdx.x;
  for (int idx = tid; idx < HH * NN; idx += 256)
    ((float*)al)[idx] = aw[(size_t)bi * HH * NN + idx];
  if (tid < 9) R[tid] = rots[bi * 9 + tid];
  if (tid < 3) T[tid] = trans[bi * 3 + tid];
  __syncthreads();

  float* crow = catm + (size_t)bi * CATW;

  // o_hat: 1536 outputs, 6 per thread
  float acc[6];
  #pragma unroll
  for (int s = 0; s < 6; s++) acc[s] = 0.f;
  const float* zrow = z + (size_t)bi * NN * CZ;
  for (int jt = 0; jt < NN / 32; jt++) {
    __syncthreads();
    for (int idx = tid; idx < 32 * CZ; idx += 256) {
      int jl = idx / CZ, c = idx % CZ;
      zt[jl][c] = zrow[(size_t)(jt * 32 + jl) * CZ + c];
    }
    __syncthreads();
    #pragma unroll
    for (int s = 0; s < 6; s++) {
      int out = tid + s * 256;
      int h = out / CZ, c = out % CZ;
      float sum = acc[s];
      #pragma unroll 8
      for (int jl = 0; jl < 32; jl++) sum += al[h][jt * 32 + jl] * zt[jl][c];
      acc[s] = sum;
    }
  }
  #pragma unroll
  for (int s = 0; s < 6; s++) crow[tid + s * 256] = acc[s];

  // o: 192 outputs (h*16+d)
  if (tid < 192) {
    int h = tid / 16;
    float sum = 0.f;
    for (int j = 0; j < NN; j++)
      sum += al[h][j] * vw[((size_t)(b * NN + j)) * 192 + tid];
    crow[1536 + tid] = sum;
  }
  // o_hp raw: 288 outputs ((h*8+pv)*3+x)  -- FIX: 288 > blockDim(256), must stride
  for (int f = tid; f < 288; f += 256) {
    int h = f / 24;
    float sum = 0.f;
    for (int j = 0; j < NN; j++)
      sum += al[h][j] * tvw[((size_t)(b * NN + j)) * 288 + f];
    praw[f] = sum;
  }
  __syncthreads();
  // invert apply: out[x] = sum_y R[y][x]*(v[y]-t[y])  -- FIX: strided over 288
  for (int f = tid; f < 288; f += 256) {
    int g = f / 3, x = f % 3;
    float v0 = praw[g * 3 + 0] - T[0];
    float v1 = praw[g * 3 + 1] - T[1];
    float v2 = praw[g * 3 + 2] - T[2];
    float val = R[0 * 3 + x] * v0 + R[1 * 3 + x] * v1 + R[2 * 3 + x] * v2;
    ohp[f] = val;
    crow[1728 + f] = val;
  }
  __syncthreads();
  if (tid < 96) {
    float x0 = ohp[tid * 3 + 0];
    float x1 = ohp[tid * 3 + 1];
    float x2 = ohp[tid * 3 + 2];
    crow[2016 + tid] = sqrtf(x0 * x0 + x1 * x1 + x2 * x2);
  }
}

// ---------------- Kernel 4: output GEMM ----------------
// (1024 x 2112) @ (2112 x 384) + bias; 32x32 tiles, 256 threads
__global__ void k_gemm(const float* __restrict__ catm,
                       const float* __restrict__ wout,
                       const float* __restrict__ bout,
                       float* __restrict__ out) {
  __shared__ float As[32][33], Bs[32][33];
  int tid = threadIdx.x;
  int tx = tid % 32, ty = tid / 32;
  int row0 = blockIdx.y * 32, col0 = blockIdx.x * 32;
  float acc[4] = {0.f, 0.f, 0.f, 0.f};
  for (int kt = 0; kt < CATW / 32; kt++) {
    #pragma unroll
    for (int s = 0; s < 4; s++)
      As[ty + 8 * s][tx] = catm[(size_t)(row0 + ty + 8 * s) * CATW + kt * 32 + tx];
    #pragma unroll
    for (int s = 0; s < 4; s++)
      Bs[ty + 8 * s][tx] = wout[(size_t)(kt * 32 + ty + 8 * s) * 384 + col0 + tx];
    __syncthreads();
    #pragma unroll
    for (int kk = 0; kk < 32; kk++) {
      float bv = Bs[kk][tx];
      #pragma unroll
      for (int s = 0; s < 4; s++) acc[s] += As[ty + 8 * s][kk] * bv;
    }
    __syncthreads();
  }
  float bias = bout[col0 + tx];
  #pragma unroll
  for (int s = 0; s < 4; s++)
    out[(size_t)(row0 + ty + 8 * s) * 384 + col0 + tx] = acc[s] + bias;
}

extern "C" void kernel_launch(void* const* d_in, const int* in_sizes, int n_in,
                              void* d_out, int out_size, void* d_ws, size_t ws_size,
                              hipStream_t stream) {
  const float* s_i   = (const float*)d_in[0];
  const float* z     = (const float*)d_in[1];
  const float* rots  = (const float*)d_in[2];
  const float* trans = (const float*)d_in[3];
  const float* wq    = (const float*)d_in[4];
  const float* wk    = (const float*)d_in[5];
  const float* wv    = (const float*)d_in[6];
  const float* wqp   = (const float*)d_in[7];
  const float* wkp   = (const float*)d_in[8];
  const float* wvp   = (const float*)d_in[9];
  const float* wb    = (const float*)d_in[10];
  const float* gamma = (const float*)d_in[11];
  const float* wout  = (const float*)d_in[12];
  const float* bout  = (const float*)d_in[13];
  float* out = (float*)d_out;

  float* ws = (float*)d_ws;
  const size_t TOK = (size_t)BB * NN;  // 1024
  float* qw  = ws;                      // TOK*192
  float* kw  = qw + TOK * 192;
  float* vw  = kw + TOK * 192;
  float* tqw = vw + TOK * 192;          // TOK*144
  float* tkw = tqw + TOK * 144;
  float* tvw = tkw + TOK * 144;         // TOK*288
  float* aw  = tvw + TOK * 288;         // TOK*H*N = 6291456
  float* catm = aw + TOK * HH * NN;     // TOK*2112

  k_proj<<<BB * NN, 256, 0, stream>>>(s_i, rots, trans, wq, wk, wv, wqp, wkp, wvp,
                                      qw, kw, vw, tqw, tkw, tvw);
  k_logits<<<BB * NN, 256, 0, stream>>>(z, wb, gamma, qw, kw, tqw, tkw, aw);
  k_out<<<BB * NN, 256, 0, stream>>>(z, vw, tvw, aw, rots, trans, catm);
  dim3 g(384 / 32, 1024 / 32);
  k_gemm<<<g, 256, 0, stream>>>(catm, wout, bout, out);
}

// Round 3
// 862.014 us; speedup vs baseline: 1.9047x; 1.9047x over previous
//
#include <hip/hip_runtime.h>
#include <hip/hip_bf16.h>
#include <math.h>

#define BB 2
#define NN 512
#define CS 384
#define CZ 128
#define HH 12
#define CATW 2112

#define W_L_CONST 0.57735026919f
#define W_C_HALF 0.11785113019f
#define INV_SQRT_D 0.25f
#define LGP 516   // padded row stride for lg[h][*]

// ---------------- Kernel 1: projections + rigid apply (2 tokens/block) ----
__global__ void k_proj(const float* __restrict__ s_i,
                       const float* __restrict__ rots,
                       const float* __restrict__ trans,
                       const float* __restrict__ wq,
                       const float* __restrict__ wk,
                       const float* __restrict__ wv,
                       const float* __restrict__ wqp,
                       const float* __restrict__ wkp,
                       const float* __restrict__ wvp,
                       float* __restrict__ qw, float* __restrict__ kw,
                       float* __restrict__ vw, float* __restrict__ tqw,
                       float* __restrict__ tkw, float* __restrict__ tvw) {
  int t0 = blockIdx.x * 2;
  __shared__ float s_row[2][CS];
  __shared__ float praw[2][576];
  __shared__ float R[2][9], T[2][3];
  int tid = threadIdx.x;
  for (int idx = tid; idx < 2 * CS; idx += 256) {
    int tok = idx / CS, c = idx % CS;
    s_row[tok][c] = s_i[(size_t)(t0 + tok) * CS + c];
  }
  if (tid < 18) R[tid / 9][tid % 9] = rots[t0 * 9 + tid];
  if (tid < 6) T[tid / 3][tid % 3] = trans[t0 * 3 + tid];
  __syncthreads();

  // 1152 tasks: [0,576) qkv, [576,1152) point raws; 2 tokens per task
  for (int f = tid; f < 1152; f += 256) {
    const float* wp;
    int stride;
    if (f < 576) {
      int sel = f / 192, r = f % 192;
      wp = ((sel == 0) ? wq : (sel == 1) ? wk : wv) + r;
      stride = 192;
    } else {
      int g = f - 576;
      if (g < 144)      { wp = wqp + g;        stride = 144; }
      else if (g < 288) { wp = wkp + (g - 144); stride = 144; }
      else              { wp = wvp + (g - 288); stride = 288; }
    }
    float a0 = 0.f, a1 = 0.f;
    #pragma unroll 8
    for (int c = 0; c < CS; c++) {
      float w = wp[(size_t)c * stride];
      a0 += s_row[0][c] * w;
      a1 += s_row[1][c] * w;
    }
    if (f < 576) {
      int sel = f / 192, r = f % 192;
      float* dst = (sel == 0) ? qw : (sel == 1) ? kw : vw;
      dst[(size_t)(t0 + 0) * 192 + r] = a0;
      dst[(size_t)(t0 + 1) * 192 + r] = a1;
    } else {
      int g = f - 576;
      praw[0][g] = a0;
      praw[1][g] = a1;
    }
  }
  __syncthreads();
  // rigid apply
  for (int idx = tid; idx < 1152; idx += 256) {
    int tok = idx / 576, f = idx % 576;
    int base, r;
    float* dst;
    if (f < 144)      { r = f;       base = 0;   dst = tqw + (size_t)(t0 + tok) * 144; }
    else if (f < 288) { r = f - 144; base = 144; dst = tkw + (size_t)(t0 + tok) * 144; }
    else              { r = f - 288; base = 288; dst = tvw + (size_t)(t0 + tok) * 288; }
    int hp = r / 3, x = r % 3;
    float v0 = praw[tok][base + hp * 3 + 0];
    float v1 = praw[tok][base + hp * 3 + 1];
    float v2 = praw[tok][base + hp * 3 + 2];
    dst[r] = R[tok][x * 3 + 0] * v0 + R[tok][x * 3 + 1] * v1 + R[tok][x * 3 + 2] * v2 + T[tok][x];
  }
}

// ---------------- Kernel 2: pair bias GEMM (z @ wb), row-parallel ----------
// grid: (B*N*N)/64 blocks; each handles 64 consecutive (bi,j) rows
__global__ void k_bias(const float* __restrict__ z,
                       const float* __restrict__ wb,
                       float* __restrict__ bw) {
  __shared__ float zt[64][129];   // padded: compute reads 2-way only
  __shared__ float wbs[CZ * HH];
  __shared__ float bbs[64][12];
  int tid = threadIdx.x;
  int r0 = blockIdx.x * 64;
  int bi = r0 >> 9, j0 = r0 & 511;

  for (int idx = tid; idx < CZ * HH; idx += 256) wbs[idx] = wb[idx];
  // load 64 rows x 128 c via float4
  const float* zbase = z + (size_t)r0 * CZ;
  for (int s = 0; s < 8; s++) {
    int idx = tid + s * 256;          // 2048 float4s
    int row = idx >> 5, q = idx & 31;
    float4 v = *(const float4*)(zbase + (size_t)row * CZ + q * 4);
    zt[row][q * 4 + 0] = v.x;
    zt[row][q * 4 + 1] = v.y;
    zt[row][q * 4 + 2] = v.z;
    zt[row][q * 4 + 3] = v.w;
  }
  __syncthreads();

  int row = tid & 63, hbase = tid >> 6;   // h = hbase, hbase+4, hbase+8 (wave-uniform)
  float a0 = 0.f, a1 = 0.f, a2 = 0.f;
  #pragma unroll 8
  for (int c = 0; c < CZ; c++) {
    float zv = zt[row][c];
    a0 += zv * wbs[c * HH + hbase];
    a1 += zv * wbs[c * HH + hbase + 4];
    a2 += zv * wbs[c * HH + hbase + 8];
  }
  bbs[row][hbase] = a0;
  bbs[row][hbase + 4] = a1;
  bbs[row][hbase + 8] = a2;
  __syncthreads();

  // write h-major: bw[(bi*12+h)*512 + j0 + jl]
  for (int idx = tid; idx < 768; idx += 256) {
    int h = idx / 64, jl = idx % 64;
    bw[((size_t)bi * HH + h) * NN + j0 + jl] = bbs[jl][h];
  }
}

// ---------------- Kernel 3: logits + softmax + o/o_hp/norm ----------------
// block per (b,i); bw holds bias (h-major) on входе, a (j-major) on exit
__global__ void k_att(const float* __restrict__ qw,
                      const float* __restrict__ kw,
                      const float* __restrict__ tqw,
                      const float* __restrict__ tkw,
                      const float* __restrict__ vw,
                      const float* __restrict__ tvw,
                      const float* __restrict__ gamma,
                      const float* __restrict__ rots,
                      const float* __restrict__ trans,
                      float* __restrict__ bw,
                      float* __restrict__ catm) {
  int bi = blockIdx.x;
  int b = bi / NN;
  __shared__ float lg[HH][LGP];         // logits -> a
  __shared__ float qrow[192], tqrow[144], gam[HH];
  __shared__ float rm[HH][4], rs[HH][4];
  __shared__ float praw[288], ohp[288], R[9], T[3];
  int tid = threadIdx.x;
  int lane = tid & 63, wid = tid >> 6;

  const float* bwrow = bw + (size_t)bi * (HH * NN);
  for (int idx = tid; idx < HH * NN; idx += 256) {
    int h = idx >> 9, j = idx & 511;
    lg[h][j] = bwrow[idx];
  }
  for (int idx = tid; idx < 192; idx += 256) qrow[idx] = qw[(size_t)bi * 192 + idx];
  if (tid < 144) tqrow[tid] = tqw[(size_t)bi * 144 + tid];
  if (tid < HH) gam[tid] = gamma[tid];
  if (tid >= 16 && tid < 25) R[tid - 16] = rots[bi * 9 + (tid - 16)];
  if (tid >= 32 && tid < 35) T[tid - 32] = trans[bi * 3 + (tid - 32)];
  __syncthreads();

  // logits: 6144 tasks = 24 * 256
  for (int s = 0; s < 24; s++) {
    int task = tid + s * 256;
    int j = task / 12, h = task % 12;
    const float4* kd = (const float4*)(kw + ((size_t)(b * NN + j)) * 192 + h * 16);
    float as = 0.f;
    #pragma unroll
    for (int q = 0; q < 4; q++) {
      float4 kv = kd[q];
      as += qrow[h * 16 + q * 4 + 0] * kv.x + qrow[h * 16 + q * 4 + 1] * kv.y +
            qrow[h * 16 + q * 4 + 2] * kv.z + qrow[h * 16 + q * 4 + 3] * kv.w;
    }
    const float4* td = (const float4*)(tkw + ((size_t)(b * NN + j)) * 144 + h * 12);
    float d2 = 0.f;
    #pragma unroll
    for (int q = 0; q < 3; q++) {
      float4 tv = td[q];
      float d0 = tqrow[h * 12 + q * 4 + 0] - tv.x;
      float d1 = tqrow[h * 12 + q * 4 + 1] - tv.y;
      float d2_ = tqrow[h * 12 + q * 4 + 2] - tv.z;
      float d3 = tqrow[h * 12 + q * 4 + 3] - tv.w;
      d2 += d0 * d0 + d1 * d1 + d2_ * d2_ + d3 * d3;
    }
    lg[h][j] = W_L_CONST * (as * INV_SQRT_D + lg[h][j] - W_C_HALF * gam[h] * d2);
  }
  __syncthreads();

  // softmax: phase 1 max
  #pragma unroll
  for (int h = 0; h < HH; h++) {
    float m = fmaxf(lg[h][tid], lg[h][tid + 256]);
    #pragma unroll
    for (int off = 32; off >= 1; off >>= 1) m = fmaxf(m, __shfl_xor(m, off, 64));
    if (lane == 0) rm[h][wid] = m;
  }
  __syncthreads();
  // phase 2: exp + sum
  #pragma unroll
  for (int h = 0; h < HH; h++) {
    float mx = fmaxf(fmaxf(rm[h][0], rm[h][1]), fmaxf(rm[h][2], rm[h][3]));
    float e0 = __expf(lg[h][tid] - mx);
    float e1 = __expf(lg[h][tid + 256] - mx);
    lg[h][tid] = e0;
    lg[h][tid + 256] = e1;
    float s = e0 + e1;
    #pragma unroll
    for (int off = 32; off >= 1; off >>= 1) s += __shfl_xor(s, off, 64);
    if (lane == 0) rs[h][wid] = s;
  }
  __syncthreads();
  // phase 3: normalize
  #pragma unroll
  for (int h = 0; h < HH; h++) {
    float inv = 1.0f / (rs[h][0] + rs[h][1] + rs[h][2] + rs[h][3]);
    lg[h][tid] *= inv;
    lg[h][tid + 256] *= inv;
  }
  __syncthreads();

  // write a j-major into bw (safe: this block fully consumed its bias range)
  float* awrow = bw + (size_t)bi * (HH * NN);
  for (int idx = tid; idx < HH * NN; idx += 256) {
    int j = idx / 12, h = idx % 12;
    awrow[idx] = lg[h][j];
  }

  float* crow = catm + (size_t)bi * CATW;
  // o (192) and o_hp raw (288): 480 dot-products of length 512
  for (int task = tid; task < 480; task += 256) {
    if (task < 192) {
      int h = task / 16;
      const float* vp = vw + (size_t)b * NN * 192 + task;
      float sum = 0.f;
      #pragma unroll 4
      for (int j = 0; j < NN; j++) sum += lg[h][j] * vp[(size_t)j * 192];
      crow[1536 + task] = sum;
    } else {
      int f = task - 192;
      int h = f / 24;
      const float* tp = tvw + (size_t)b * NN * 288 + f;
      float sum = 0.f;
      #pragma unroll 4
      for (int j = 0; j < NN; j++) sum += lg[h][j] * tp[(size_t)j * 288];
      praw[f] = sum;
    }
  }
  __syncthreads();
  // invert apply: out[x] = sum_y R[y][x]*(v[y]-t[y])
  for (int f = tid; f < 288; f += 256) {
    int g = f / 3, x = f % 3;
    float v0 = praw[g * 3 + 0] - T[0];
    float v1 = praw[g * 3 + 1] - T[1];
    float v2 = praw[g * 3 + 2] - T[2];
    float val = R[0 * 3 + x] * v0 + R[1 * 3 + x] * v1 + R[2 * 3 + x] * v2;
    ohp[f] = val;
    crow[1728 + f] = val;
  }
  __syncthreads();
  if (tid < 96) {
    float x0 = ohp[tid * 3 + 0];
    float x1 = ohp[tid * 3 + 1];
    float x2 = ohp[tid * 3 + 2];
    crow[2016 + tid] = sqrtf(x0 * x0 + x1 * x1 + x2 * x2);
  }
}

// ---------------- Kernel 4: o_hat = a @ z (second z pass) -----------------
// block per (b,i); wave w owns j in [w*128, w*128+128); lane owns 2 c cols
__global__ void k_ohat(const float* __restrict__ z,
                       const float* __restrict__ aw,
                       float* __restrict__ catm) {
  int bi = blockIdx.x;
  __shared__ float buf[HH * NN];   // phase A: a j-major [512][12]; phase B: partials
  int tid = threadIdx.x;
  const float* awrow = aw + (size_t)bi * (HH * NN);
  for (int idx = tid; idx < HH * NN; idx += 256) buf[idx] = awrow[idx];
  __syncthreads();

  int c0 = (tid & 63) * 2, jg = tid >> 6;
  const float* zrow = z + ((size_t)bi * NN + jg * 128) * CZ;
  float accx[HH], accy[HH];
  #pragma unroll
  for (int h = 0; h < HH; h++) { accx[h] = 0.f; accy[h] = 0.f; }

  for (int jj = 0; jj < 128; jj++) {
    float2 zv = *(const float2*)(zrow + (size_t)jj * CZ + c0);
    const float4* ap = (const float4*)(buf + (jg * 128 + jj) * 12);
    float4 A0 = ap[0], A1 = ap[1], A2 = ap[2];   // broadcast b128 reads
    accx[0] += A0.x * zv.x;  accy[0] += A0.x * zv.y;
    accx[1] += A0.y * zv.x;  accy[1] += A0.y * zv.y;
    accx[2] += A0.z * zv.x;  accy[2] += A0.z * zv.y;
    accx[3] += A0.w * zv.x;  accy[3] += A0.w * zv.y;
    accx[4] += A1.x * zv.x;  accy[4] += A1.x * zv.y;
    accx[5] += A1.y * zv.x;  accy[5] += A1.y * zv.y;
    accx[6] += A1.z * zv.x;  accy[6] += A1.z * zv.y;
    accx[7] += A1.w * zv.x;  accy[7] += A1.w * zv.y;
    accx[8] += A2.x * zv.x;  accy[8] += A2.x * zv.y;
    accx[9] += A2.y * zv.x;  accy[9] += A2.y * zv.y;
    accx[10] += A2.z * zv.x; accy[10] += A2.z * zv.y;
    accx[11] += A2.w * zv.x; accy[11] += A2.w * zv.y;
  }
  __syncthreads();   // all reads of a done; reuse buf for partials
  #pragma unroll
  for (int h = 0; h < HH; h++) {
    buf[jg * 1536 + h * CZ + c0] = accx[h];
    buf[jg * 1536 + h * CZ + c0 + 1] = accy[h];
  }
  __syncthreads();
  float* crow = catm + (size_t)bi * CATW;
  #pragma unroll
  for (int s = 0; s < 6; s++) {
    int out = tid + s * 256;
    crow[out] = buf[out] + buf[1536 + out] + buf[3072 + out] + buf[4608 + out];
  }
}

// ---------------- Kernel 5: output GEMM ----------------
__global__ void k_gemm(const float* __restrict__ catm,
                       const float* __restrict__ wout,
                       const float* __restrict__ bout,
                       float* __restrict__ out) {
  __shared__ float As[32][33], Bs[32][33];
  int tid = threadIdx.x;
  int tx = tid % 32, ty = tid / 32;
  int row0 = blockIdx.y * 32, col0 = blockIdx.x * 32;
  float acc[4] = {0.f, 0.f, 0.f, 0.f};
  for (int kt = 0; kt < CATW / 32; kt++) {
    #pragma unroll
    for (int s = 0; s < 4; s++)
      As[ty + 8 * s][tx] = catm[(size_t)(row0 + ty + 8 * s) * CATW + kt * 32 + tx];
    #pragma unroll
    for (int s = 0; s < 4; s++)
      Bs[ty + 8 * s][tx] = wout[(size_t)(kt * 32 + ty + 8 * s) * 384 + col0 + tx];
    __syncthreads();
    #pragma unroll
    for (int kk = 0; kk < 32; kk++) {
      float bv = Bs[kk][tx];
      #pragma unroll
      for (int s = 0; s < 4; s++) acc[s] += As[ty + 8 * s][kk] * bv;
    }
    __syncthreads();
  }
  float bias = bout[col0 + tx];
  #pragma unroll
  for (int s = 0; s < 4; s++)
    out[(size_t)(row0 + ty + 8 * s) * 384 + col0 + tx] = acc[s] + bias;
}

extern "C" void kernel_launch(void* const* d_in, const int* in_sizes, int n_in,
                              void* d_out, int out_size, void* d_ws, size_t ws_size,
                              hipStream_t stream) {
  const float* s_i   = (const float*)d_in[0];
  const float* z     = (const float*)d_in[1];
  const float* rots  = (const float*)d_in[2];
  const float* trans = (const float*)d_in[3];
  const float* wq    = (const float*)d_in[4];
  const float* wk    = (const float*)d_in[5];
  const float* wv    = (const float*)d_in[6];
  const float* wqp   = (const float*)d_in[7];
  const float* wkp   = (const float*)d_in[8];
  const float* wvp   = (const float*)d_in[9];
  const float* wb    = (const float*)d_in[10];
  const float* gamma = (const float*)d_in[11];
  const float* wout  = (const float*)d_in[12];
  const float* bout  = (const float*)d_in[13];
  float* out = (float*)d_out;

  float* ws = (float*)d_ws;
  const size_t TOK = (size_t)BB * NN;  // 1024
  float* qw  = ws;                      // TOK*192
  float* kw  = qw + TOK * 192;
  float* vw  = kw + TOK * 192;
  float* tqw = vw + TOK * 192;          // TOK*144
  float* tkw = tqw + TOK * 144;
  float* tvw = tkw + TOK * 144;         // TOK*288
  float* bw  = tvw + TOK * 288;         // TOK*H*N (bias, then a — aliased)
  float* catm = bw + TOK * HH * NN;     // TOK*2112

  k_proj<<<BB * NN / 2, 256, 0, stream>>>(s_i, rots, trans, wq, wk, wv, wqp, wkp, wvp,
                                          qw, kw, vw, tqw, tkw, tvw);
  k_bias<<<BB * NN * NN / 64, 256, 0, stream>>>(z, wb, bw);
  k_att<<<BB * NN, 256, 0, stream>>>(qw, kw, tqw, tkw, vw, tvw, gamma, rots, trans,
                                     bw, catm);
  k_ohat<<<BB * NN, 256, 0, stream>>>(z, bw, catm);
  dim3 g(384 / 32, 1024 / 32);
  k_gemm<<<g, 256, 0, stream>>>(catm, wout, bout, out);
}

// Round 4
// 704.437 us; speedup vs baseline: 2.3307x; 1.2237x over previous
//
#include <hip/hip_runtime.h>
#include <hip/hip_bf16.h>
#include <math.h>

#define BB 2
#define NN 512
#define CS 384
#define CZ 128
#define HH 12
#define CATW 2112

#define W_L_CONST 0.57735026919f
#define W_C_HALF 0.11785113019f
#define INV_SQRT_D 0.25f
#define LGP 516   // padded row stride for lg[h][*]

// ---------------- Kernel 1: projections + rigid apply (2 tokens/block) ----
__global__ void k_proj(const float* __restrict__ s_i,
                       const float* __restrict__ rots,
                       const float* __restrict__ trans,
                       const float* __restrict__ wq,
                       const float* __restrict__ wk,
                       const float* __restrict__ wv,
                       const float* __restrict__ wqp,
                       const float* __restrict__ wkp,
                       const float* __restrict__ wvp,
                       float* __restrict__ qw, float* __restrict__ kw,
                       float* __restrict__ vw, float* __restrict__ tqw,
                       float* __restrict__ tkw, float* __restrict__ tvw) {
  int t0 = blockIdx.x * 2;
  __shared__ float s_row[2][CS];
  __shared__ float praw[2][576];
  __shared__ float R[2][9], T[2][3];
  int tid = threadIdx.x;
  for (int idx = tid; idx < 2 * CS; idx += 256) {
    int tok = idx / CS, c = idx % CS;
    s_row[tok][c] = s_i[(size_t)(t0 + tok) * CS + c];
  }
  if (tid < 18) R[tid / 9][tid % 9] = rots[t0 * 9 + tid];
  if (tid < 6) T[tid / 3][tid % 3] = trans[t0 * 3 + tid];
  __syncthreads();

  for (int f = tid; f < 1152; f += 256) {
    const float* wp;
    int stride;
    if (f < 576) {
      int sel = f / 192, r = f % 192;
      wp = ((sel == 0) ? wq : (sel == 1) ? wk : wv) + r;
      stride = 192;
    } else {
      int g = f - 576;
      if (g < 144)      { wp = wqp + g;        stride = 144; }
      else if (g < 288) { wp = wkp + (g - 144); stride = 144; }
      else              { wp = wvp + (g - 288); stride = 288; }
    }
    float a0 = 0.f, a1 = 0.f;
    #pragma unroll 8
    for (int c = 0; c < CS; c++) {
      float w = wp[(size_t)c * stride];
      a0 += s_row[0][c] * w;
      a1 += s_row[1][c] * w;
    }
    if (f < 576) {
      int sel = f / 192, r = f % 192;
      float* dst = (sel == 0) ? qw : (sel == 1) ? kw : vw;
      dst[(size_t)(t0 + 0) * 192 + r] = a0;
      dst[(size_t)(t0 + 1) * 192 + r] = a1;
    } else {
      int g = f - 576;
      praw[0][g] = a0;
      praw[1][g] = a1;
    }
  }
  __syncthreads();
  for (int idx = tid; idx < 1152; idx += 256) {
    int tok = idx / 576, f = idx % 576;
    int base, r;
    float* dst;
    if (f < 144)      { r = f;       base = 0;   dst = tqw + (size_t)(t0 + tok) * 144; }
    else if (f < 288) { r = f - 144; base = 144; dst = tkw + (size_t)(t0 + tok) * 144; }
    else              { r = f - 288; base = 288; dst = tvw + (size_t)(t0 + tok) * 288; }
    int hp = r / 3, x = r % 3;
    float v0 = praw[tok][base + hp * 3 + 0];
    float v1 = praw[tok][base + hp * 3 + 1];
    float v2 = praw[tok][base + hp * 3 + 2];
    dst[r] = R[tok][x * 3 + 0] * v0 + R[tok][x * 3 + 1] * v1 + R[tok][x * 3 + 2] * v2 + T[tok][x];
  }
}

// ---------------- Kernel 2: pair bias GEMM (z @ wb), row-parallel ----------
__global__ void k_bias(const float* __restrict__ z,
                       const float* __restrict__ wb,
                       float* __restrict__ bw) {
  __shared__ float zt[64][129];
  __shared__ float wbs[CZ * HH];
  __shared__ float bbs[64][12];
  int tid = threadIdx.x;
  int r0 = blockIdx.x * 64;
  int bi = r0 >> 9, j0 = r0 & 511;

  for (int idx = tid; idx < CZ * HH; idx += 256) wbs[idx] = wb[idx];
  const float* zbase = z + (size_t)r0 * CZ;
  for (int s = 0; s < 8; s++) {
    int idx = tid + s * 256;
    int row = idx >> 5, q = idx & 31;
    float4 v = *(const float4*)(zbase + (size_t)row * CZ + q * 4);
    zt[row][q * 4 + 0] = v.x;
    zt[row][q * 4 + 1] = v.y;
    zt[row][q * 4 + 2] = v.z;
    zt[row][q * 4 + 3] = v.w;
  }
  __syncthreads();

  int row = tid & 63, hbase = tid >> 6;
  float a0 = 0.f, a1 = 0.f, a2 = 0.f;
  #pragma unroll 8
  for (int c = 0; c < CZ; c++) {
    float zv = zt[row][c];
    a0 += zv * wbs[c * HH + hbase];
    a1 += zv * wbs[c * HH + hbase + 4];
    a2 += zv * wbs[c * HH + hbase + 8];
  }
  bbs[row][hbase] = a0;
  bbs[row][hbase + 4] = a1;
  bbs[row][hbase + 8] = a2;
  __syncthreads();

  for (int idx = tid; idx < 768; idx += 256) {
    int h = idx / 64, jl = idx % 64;
    bw[((size_t)bi * HH + h) * NN + j0 + jl] = bbs[jl][h];
  }
}

// ---------------- Kernel 3: fused logits+softmax+o/o_hp+o_hat ------------
// block per (b,i), 256 threads
__global__ void k_att(const float* __restrict__ z,
                      const float* __restrict__ qw,
                      const float* __restrict__ kw,
                      const float* __restrict__ tqw,
                      const float* __restrict__ tkw,
                      const float* __restrict__ vw,
                      const float* __restrict__ tvw,
                      const float* __restrict__ gamma,
                      const float* __restrict__ rots,
                      const float* __restrict__ trans,
                      const float* __restrict__ bw,
                      float* __restrict__ catm) {
  int bi = blockIdx.x;
  int b = bi / NN;
  __shared__ float lg[HH][LGP];         // logits -> a -> (reused) o_hat partials
  __shared__ float opart[4][480];
  __shared__ float qrow[192], tqrow[144], gam[HH];
  __shared__ float rm[HH][4], rs[HH][4];
  __shared__ float praw[288], ohp[288], R[9], T[3];
  int tid = threadIdx.x;
  int lane = tid & 63, wid = tid >> 6;

  const float* bwrow = bw + (size_t)bi * (HH * NN);
  for (int idx = tid; idx < HH * NN; idx += 256)
    lg[idx >> 9][idx & 511] = bwrow[idx];
  for (int idx = tid; idx < 192; idx += 256) qrow[idx] = qw[(size_t)bi * 192 + idx];
  if (tid < 144) tqrow[tid] = tqw[(size_t)bi * 144 + tid];
  if (tid < HH) gam[tid] = gamma[tid];
  if (tid < 9) R[tid] = rots[bi * 9 + tid];
  if (tid < 3) T[tid] = trans[bi * 3 + tid];
  __syncthreads();

  // ---- logits: 6144 tasks = 24 * 256 ----
  for (int s = 0; s < 24; s++) {
    int task = tid + s * 256;
    int j = task / 12, h = task % 12;
    const float4* kd = (const float4*)(kw + ((size_t)(b * NN + j)) * 192 + h * 16);
    float as = 0.f;
    #pragma unroll
    for (int q = 0; q < 4; q++) {
      float4 kv = kd[q];
      as += qrow[h * 16 + q * 4 + 0] * kv.x + qrow[h * 16 + q * 4 + 1] * kv.y +
            qrow[h * 16 + q * 4 + 2] * kv.z + qrow[h * 16 + q * 4 + 3] * kv.w;
    }
    const float4* td = (const float4*)(tkw + ((size_t)(b * NN + j)) * 144 + h * 12);
    float d2 = 0.f;
    #pragma unroll
    for (int q = 0; q < 3; q++) {
      float4 tv = td[q];
      float d0 = tqrow[h * 12 + q * 4 + 0] - tv.x;
      float d1 = tqrow[h * 12 + q * 4 + 1] - tv.y;
      float d2_ = tqrow[h * 12 + q * 4 + 2] - tv.z;
      float d3 = tqrow[h * 12 + q * 4 + 3] - tv.w;
      d2 += d0 * d0 + d1 * d1 + d2_ * d2_ + d3 * d3;
    }
    lg[h][j] = W_L_CONST * (as * INV_SQRT_D + lg[h][j] - W_C_HALF * gam[h] * d2);
  }
  __syncthreads();

  // ---- softmax ----
  #pragma unroll
  for (int h = 0; h < HH; h++) {
    float m = fmaxf(lg[h][tid], lg[h][tid + 256]);
    #pragma unroll
    for (int off = 32; off >= 1; off >>= 1) m = fmaxf(m, __shfl_xor(m, off, 64));
    if (lane == 0) rm[h][wid] = m;
  }
  __syncthreads();
  #pragma unroll
  for (int h = 0; h < HH; h++) {
    float mx = fmaxf(fmaxf(rm[h][0], rm[h][1]), fmaxf(rm[h][2], rm[h][3]));
    float e0 = __expf(lg[h][tid] - mx);
    float e1 = __expf(lg[h][tid + 256] - mx);
    lg[h][tid] = e0;
    lg[h][tid + 256] = e1;
    float s = e0 + e1;
    #pragma unroll
    for (int off = 32; off >= 1; off >>= 1) s += __shfl_xor(s, off, 64);
    if (lane == 0) rs[h][wid] = s;
  }
  __syncthreads();
  #pragma unroll
  for (int h = 0; h < HH; h++) {
    float inv = 1.0f / (rs[h][0] + rs[h][1] + rs[h][2] + rs[h][3]);
    lg[h][tid] *= inv;
    lg[h][tid + 256] *= inv;
  }
  __syncthreads();   // lg now holds a

  float* crow = catm + (size_t)bi * CATW;
  int j0 = wid * 128;   // this wave's j window

  // ---- o / o_hp partials: wave-split over j ----
  for (int t = lane; t < 480; t += 64) {
    const float* src;
    int h, str;
    if (t < 192) { h = t >> 4; src = vw + (size_t)b * NN * 192 + t; str = 192; }
    else { int f = t - 192; h = f / 24; src = tvw + (size_t)b * NN * 288 + f; str = 288; }
    float sum = 0.f;
    for (int jj = 0; jj < 128; jj += 4) {
      float4 av = *(const float4*)&lg[h][j0 + jj];
      sum += av.x * src[(size_t)(j0 + jj + 0) * str]
           + av.y * src[(size_t)(j0 + jj + 1) * str]
           + av.z * src[(size_t)(j0 + jj + 2) * str]
           + av.w * src[(size_t)(j0 + jj + 3) * str];
    }
    opart[wid][t] = sum;
  }
  __syncthreads();
  for (int t = tid; t < 480; t += 256) {
    float s = opart[0][t] + opart[1][t] + opart[2][t] + opart[3][t];
    if (t < 192) crow[1536 + t] = s;
    else praw[t - 192] = s;
  }
  __syncthreads();
  for (int f = tid; f < 288; f += 256) {
    int g = f / 3, x = f % 3;
    float v0 = praw[g * 3 + 0] - T[0];
    float v1 = praw[g * 3 + 1] - T[1];
    float v2 = praw[g * 3 + 2] - T[2];
    float val = R[0 * 3 + x] * v0 + R[1 * 3 + x] * v1 + R[2 * 3 + x] * v2;
    ohp[f] = val;
    crow[1728 + f] = val;
  }
  __syncthreads();
  if (tid < 96) {
    float x0 = ohp[tid * 3 + 0];
    float x1 = ohp[tid * 3 + 1];
    float x2 = ohp[tid * 3 + 2];
    crow[2016 + tid] = sqrtf(x0 * x0 + x1 * x1 + x2 * x2);
  }

  // ---- o_hat: stream z (second pass), half-wave j-split, float4 c ----
  int hw = lane >> 5, c4 = (lane & 31) * 4;
  float4 acc[HH];
  #pragma unroll
  for (int h = 0; h < HH; h++) acc[h] = make_float4(0.f, 0.f, 0.f, 0.f);
  for (int stp = 0; stp < 64; stp++) {
    int j = j0 + stp * 2 + hw;
    float4 zv = *(const float4*)(z + ((size_t)bi * NN + j) * CZ + c4);
    #pragma unroll
    for (int h = 0; h < HH; h++) {
      float a = lg[h][j];
      acc[h].x += a * zv.x;
      acc[h].y += a * zv.y;
      acc[h].z += a * zv.z;
      acc[h].w += a * zv.w;
    }
  }
  __syncthreads();   // all reads of lg complete everywhere; safe to reuse
  #pragma unroll
  for (int h = 0; h < HH; h++) {
    acc[h].x += __shfl_xor(acc[h].x, 32, 64);
    acc[h].y += __shfl_xor(acc[h].y, 32, 64);
    acc[h].z += __shfl_xor(acc[h].z, 32, 64);
    acc[h].w += __shfl_xor(acc[h].w, 32, 64);
  }
  float* pbuf = &lg[0][0];
  if (lane < 32) {
    #pragma unroll
    for (int h = 0; h < HH; h++)
      *(float4*)&pbuf[wid * 1536 + h * 128 + lane * 4] = acc[h];
  }
  __syncthreads();
  #pragma unroll
  for (int s = 0; s < 6; s++) {
    int idx = tid + s * 256;
    crow[idx] = pbuf[idx] + pbuf[1536 + idx] + pbuf[3072 + idx] + pbuf[4608 + idx];
  }
}

// ---------------- Kernel 4: output GEMM, split-K=4, 64x64, 4x4 reg tile ---
#define KCH 528
__global__ void k_gemm(const float* __restrict__ catm,
                       const float* __restrict__ wout,
                       float* __restrict__ pout) {
  __shared__ float As[16][68];   // [kk][m], padded
  __shared__ float Bs[16][64];   // [kk][n]
  int tid = threadIdx.x;
  int n0 = blockIdx.x * 64, m0 = blockIdx.y * 64, kbase = blockIdx.z * KCH;
  int tx = tid & 15, ty = tid >> 4;
  int sm = tid & 63, skk4 = tid >> 6;
  int bkk = tid >> 4, bn4 = (tid & 15) * 4;
  float acc[4][4] = {};
  for (int kt = 0; kt < KCH / 16; kt++) {
    int k0 = kbase + kt * 16;
    float4 ga = *(const float4*)(catm + (size_t)(m0 + sm) * CATW + k0 + skk4 * 4);
    float4 gb = *(const float4*)(wout + (size_t)(k0 + bkk) * 384 + n0 + bn4);
    __syncthreads();
    As[skk4 * 4 + 0][sm] = ga.x;
    As[skk4 * 4 + 1][sm] = ga.y;
    As[skk4 * 4 + 2][sm] = ga.z;
    As[skk4 * 4 + 3][sm] = ga.w;
    *(float4*)&Bs[bkk][bn4] = gb;
    __syncthreads();
    #pragma unroll
    for (int kk = 0; kk < 16; kk++) {
      float4 av = *(const float4*)&As[kk][ty * 4];
      float4 bv = *(const float4*)&Bs[kk][tx * 4];
      acc[0][0] += av.x * bv.x; acc[0][1] += av.x * bv.y; acc[0][2] += av.x * bv.z; acc[0][3] += av.x * bv.w;
      acc[1][0] += av.y * bv.x; acc[1][1] += av.y * bv.y; acc[1][2] += av.y * bv.z; acc[1][3] += av.y * bv.w;
      acc[2][0] += av.z * bv.x; acc[2][1] += av.z * bv.y; acc[2][2] += av.z * bv.z; acc[2][3] += av.z * bv.w;
      acc[3][0] += av.w * bv.x; acc[3][1] += av.w * bv.y; acc[3][2] += av.w * bv.z; acc[3][3] += av.w * bv.w;
    }
  }
  float* pdst = pout + (size_t)blockIdx.z * (1024 * 384);
  #pragma unroll
  for (int mm = 0; mm < 4; mm++) {
    *(float4*)&pdst[(size_t)(m0 + ty * 4 + mm) * 384 + n0 + tx * 4] =
        make_float4(acc[mm][0], acc[mm][1], acc[mm][2], acc[mm][3]);
  }
}

// ---------------- Kernel 5: split-K reduce + bias ----
__global__ void k_red(const float* __restrict__ pout,
                      const float* __restrict__ bout,
                      float* __restrict__ out) {
  int idx = blockIdx.x * 256 + threadIdx.x;
  const int TOTAL = 1024 * 384;
  float s = pout[idx] + pout[TOTAL + idx] + pout[2 * TOTAL + idx] + pout[3 * TOTAL + idx];
  out[idx] = s + bout[idx % 384];
}

extern "C" void kernel_launch(void* const* d_in, const int* in_sizes, int n_in,
                              void* d_out, int out_size, void* d_ws, size_t ws_size,
                              hipStream_t stream) {
  const float* s_i   = (const float*)d_in[0];
  const float* z     = (const float*)d_in[1];
  const float* rots  = (const float*)d_in[2];
  const float* trans = (const float*)d_in[3];
  const float* wq    = (const float*)d_in[4];
  const float* wk    = (const float*)d_in[5];
  const float* wv    = (const float*)d_in[6];
  const float* wqp   = (const float*)d_in[7];
  const float* wkp   = (const float*)d_in[8];
  const float* wvp   = (const float*)d_in[9];
  const float* wb    = (const float*)d_in[10];
  const float* gamma = (const float*)d_in[11];
  const float* wout  = (const float*)d_in[12];
  const float* bout  = (const float*)d_in[13];
  float* out = (float*)d_out;

  float* ws = (float*)d_ws;
  const size_t TOK = (size_t)BB * NN;  // 1024
  float* qw  = ws;                      // TOK*192
  float* kw  = qw + TOK * 192;
  float* vw  = kw + TOK * 192;
  float* tqw = vw + TOK * 192;          // TOK*144
  float* tkw = tqw + TOK * 144;
  float* tvw = tkw + TOK * 144;         // TOK*288
  float* bw  = tvw + TOK * 288;         // TOK*H*N bias
  float* catm = bw + TOK * HH * NN;     // TOK*2112
  float* pout = catm + TOK * CATW;      // 4*1024*384

  k_proj<<<BB * NN / 2, 256, 0, stream>>>(s_i, rots, trans, wq, wk, wv, wqp, wkp, wvp,
                                          qw, kw, vw, tqw, tkw, tvw);
  k_bias<<<BB * NN * NN / 64, 256, 0, stream>>>(z, wb, bw);
  k_att<<<BB * NN, 256, 0, stream>>>(z, qw, kw, tqw, tkw, vw, tvw, gamma, rots, trans,
                                     bw, catm);
  dim3 gg(6, 16, 4);
  k_gemm<<<gg, 256, 0, stream>>>(catm, wout, pout);
  k_red<<<(1024 * 384) / 256, 256, 0, stream>>>(pout, bout, out);
}